// Round 5
// baseline (214.997 us; speedup 1.0000x reference)
//
#include <hip/hip_runtime.h>
#include <hip/hip_bf16.h>
#include <stdint.h>

#define M_DIM 16384   // 8 * 2048
#define N_DIM 2048    // OUT_F
#define K_DIM 2048    // IN_F

typedef __attribute__((ext_vector_type(8))) __bf16 bf16x8;
typedef __attribute__((ext_vector_type(4))) float f32x4;

__device__ __forceinline__ unsigned short f2bf(float f) {
  unsigned int u = __builtin_bit_cast(unsigned int, f);
  u += 0x7FFFu + ((u >> 16) & 1u);   // round-to-nearest-even
  return (unsigned short)(u >> 16);
}

__device__ __forceinline__ float sigmoidf_(float x) {
  return 1.0f / (1.0f + __expf(-x));
}

// ---------------- kernel 1: X f32 -> bf16 ----------------
__global__ __launch_bounds__(256) void convert_x(const float4* __restrict__ x,
                                                 uint4* __restrict__ xb) {
  int idx = blockIdx.x * 256 + threadIdx.x;   // one uint4 (8 bf16) per thread
  float4 a = x[idx * 2];
  float4 b = x[idx * 2 + 1];
  uint4 r;
  r.x = (unsigned)f2bf(a.x) | ((unsigned)f2bf(a.y) << 16);
  r.y = (unsigned)f2bf(a.z) | ((unsigned)f2bf(a.w) << 16);
  r.z = (unsigned)f2bf(b.x) | ((unsigned)f2bf(b.y) << 16);
  r.w = (unsigned)f2bf(b.z) | ((unsigned)f2bf(b.w) << 16);
  xb[idx] = r;
}

// ---------------- kernel 2: weight materialization (producer-aligned) -------
// R4 post-mortem: B lines written on random XCDs sat DIRTY in remote L2s;
// every GEMM first-touch was a ~1000cy cross-XCD snoop -> ingest capped at
// in-flight/latency ~ 6.4 TB/s. Remap so XCD x (blockIdx%8) materializes
// exactly B panel o in [x*256, x*256+256) -- the panel GEMM-XCD x reads.
__global__ __launch_bounds__(256) void make_w(const float4* __restrict__ pw,
                                              const float4* __restrict__ nw,
                                              const float* __restrict__ exps,
                                              const float* __restrict__ maskw,
                                              const float* __restrict__ scale,
                                              unsigned short* __restrict__ wout) {
  const int beta = blockIdx.x;          // 16384 blocks
  const int xcd = beta & 7;
  const int j = beta >> 3;              // 0..2047
  const int o = xcd * 256 + (j >> 3);   // output row (B panel row)
  const int iblk = j & 7;               // 256-wide i chunk
  int idx = (o * 2048 + iblk * 256) + threadIdx.x;   // flat (o*K + i) in float4s
  float4 p = pw[idx];
  float4 n = nw[idx];
  float s = scale[0];
  float c0 = sigmoidf_(maskw[0]) * exps[0] * s;
  float c1 = sigmoidf_(maskw[1]) * exps[1] * s;
  float c2 = sigmoidf_(maskw[2]) * exps[2] * s;
  float c3 = sigmoidf_(maskw[3]) * exps[3] * s;
  float w = (sigmoidf_(p.x) - sigmoidf_(n.x)) * c0
          + (sigmoidf_(p.y) - sigmoidf_(n.y)) * c1
          + (sigmoidf_(p.z) - sigmoidf_(n.z)) * c2
          + (sigmoidf_(p.w) - sigmoidf_(n.w)) * c3;
  wout[idx] = f2bf(w);
}

// ---------------- kernel 3: bias ----------------
__global__ __launch_bounds__(256) void make_bias(const float* __restrict__ pb,
                                                 const float* __restrict__ nb,
                                                 const float* __restrict__ bexps,
                                                 const float* __restrict__ bscale,
                                                 float* __restrict__ bias) {
  int o = blockIdx.x * 256 + threadIdx.x;
  if (o < N_DIM) {
    float x = 0.f;
#pragma unroll
    for (int n = 0; n < 4; ++n) x += (pb[o * 4 + n] - nb[o * 4 + n]) * bexps[n];
    float xc = fminf(fmaxf(x, -1.f), 1.f);
    float mag = rintf(fabsf(xc) * 15.f) * (1.f / 15.f);
    float sgn = (xc > 0.f) ? 1.f : ((xc < 0.f) ? -1.f : 0.f);
    bias[o] = mag * sgn * bscale[0];
  }
}

// ---------------- kernel 4: 256x256 8-phase GEMM (R2 schedule + new swizzle)
// Schedule = the measured-best R2 version (155us), unchanged. Only change:
// XCD mapping. bn = blockIdx%8 = XCD: B panel (1 MB) is private to its XCD,
// L2-resident after first touch, and written there by make_w. All XCDs
// stream the same A-window in lockstep (LLC-shared).

#define BM 256
#define BN 256
#define BK 64
#define NT (K_DIM / BK)   // 32

__device__ __forceinline__ void gload16(const void* g, void* l) {
  __builtin_amdgcn_global_load_lds(
      (const __attribute__((address_space(1))) unsigned int*)g,
      (__attribute__((address_space(3))) unsigned int*)l, 16, 0, 0);
}

#define VMCNT(n) asm volatile("s_waitcnt vmcnt(" #n ")" ::: "memory")
#define BAR() __builtin_amdgcn_s_barrier()

__global__ __launch_bounds__(512, 2) void gemm_bias(const unsigned short* __restrict__ X,
                                                    const unsigned short* __restrict__ W,
                                                    const float* __restrict__ bias,
                                                    float* __restrict__ out) {
  __shared__ unsigned short sA[2][BM * BK];   // 64 KiB
  __shared__ unsigned short sB[2][BN * BK];   // 64 KiB

  const int tid = threadIdx.x;
  // Locality swizzle: one bn-column of the grid per XCD (512 blocks = 8 x 64).
  const int bn = (int)blockIdx.x & 7;    // == XCD (dispatch round-robin)
  const int bm = (int)blockIdx.x >> 3;   // 0..63, in dispatch order
  const int row0 = bm * BM, col0 = bn * BN;

  const int w = tid >> 6, l = tid & 63;
  const int wr = w >> 2;        // 0..1  (M wave group)
  const int wc = w & 3;         // 0..3  (N wave group)
  const int lr = l & 15;
  const int lk4 = l >> 4;       // 0..3
  const int l7 = l & 7;

  const unsigned short* Ag = X + (size_t)row0 * K_DIM;
  const unsigned short* Bg = W + (size_t)col0 * K_DIM;

  // staging geometry: thread t -> row rb+((t>>3)&31); global col16 pre-swizzled
  const int srl = (tid >> 3) & 31;
  const int sc16 = (tid & 7) ^ ((tid >> 3) & 7);      // inverse-swizzled source
  const int shi = tid >> 8;                           // wave-uniform chunk select
  const int slin = ((tid >> 3) & 24) * 64 + (tid & 63) * 8;  // linear LDS dest

  auto stage = [&](unsigned short* lbase, const unsigned short* gbase,
                   int rb0, int rb1, int tk) {
    int rb = shi ? rb1 : rb0;
    int trow = rb + srl;
    gload16(gbase + (size_t)trow * K_DIM + tk * BK + sc16 * 8,
            lbase + rb * 64 + slin);
  };

  auto rdA = [&](const unsigned short* base, int mf, int ks) -> bf16x8 {
    int trow = wr * 128 + mf * 16 + lr;
    int c16l = (ks * 4 + lk4) ^ l7;
    return *(const bf16x8*)&base[trow * 64 + c16l * 8];
  };
  auto rdB = [&](const unsigned short* base, int nf, int ks) -> bf16x8 {
    int trow = wc * 64 + nf * 16 + lr;
    int c16l = (ks * 4 + lk4) ^ l7;
    return *(const bf16x8*)&base[trow * 64 + c16l * 8];
  };

  f32x4 acc[8][4] = {};
  bf16x8 a[4][2], b[4][2];

#define PHASE_MFMA(mh, nh)                                                    \
  __builtin_amdgcn_s_setprio(1);                                              \
  _Pragma("unroll") for (int i = 0; i < 4; ++i)                               \
  _Pragma("unroll") for (int j = 0; j < 2; ++j)                               \
  _Pragma("unroll") for (int ks = 0; ks < 2; ++ks)                            \
      acc[(mh) * 4 + i][(nh) * 2 + j] = __builtin_amdgcn_mfma_f32_16x16x32_bf16( \
          a[i][ks], b[(nh) * 2 + j][ks], acc[(mh) * 4 + i][(nh) * 2 + j], 0, 0, 0); \
  __builtin_amdgcn_s_setprio(0);

  // ---- prologue: stage tile 0 (rounds R0..R7, program order = round order)
  {
    unsigned short* qa = sA[0];
    unsigned short* qb = sB[0];
    stage(qa, Ag, 0, 32, 0);    // R0
    stage(qa, Ag, 128, 160, 0); // R1
    stage(qb, Bg, 0, 64, 0);    // R2
    stage(qb, Bg, 128, 192, 0); // R3
    stage(qb, Bg, 32, 96, 0);   // R4
    stage(qb, Bg, 160, 224, 0); // R5
    stage(qa, Ag, 64, 96, 0);   // R6
    stage(qa, Ag, 192, 224, 0); // R7
  }
  VMCNT(4);   // R0-R3(0) complete; R4-R7(0) in flight
  BAR();

  for (int t = 0; t < NT; ++t) {
    const int p = t & 1, q = p ^ 1;
    const bool last = (t == NT - 1);
    const unsigned short* pa = sA[p];
    const unsigned short* pb = sB[p];
    unsigned short* qa = sA[q];
    unsigned short* qb = sB[q];

    // ---------- phase 0: A(mh0) + B(nf0,1) reads; MFMA quadrant (0,0)
#pragma unroll
    for (int i = 0; i < 4; ++i)
#pragma unroll
      for (int ks = 0; ks < 2; ++ks) a[i][ks] = rdA(pa, i, ks);
#pragma unroll
    for (int j = 0; j < 2; ++j)
#pragma unroll
      for (int ks = 0; ks < 2; ++ks) b[j][ks] = rdB(pb, j, ks);
    if (!last) { stage(qa, Ag, 0, 32, t + 1); stage(qa, Ag, 128, 160, t + 1); }
    BAR();
    PHASE_MFMA(0, 0);
    if (!last) { VMCNT(4); } else { VMCNT(2); }   // R4,R5(t) done
    BAR();

    // ---------- phase 1: B(nf2,3) reads; MFMA quadrant (0,1)
#pragma unroll
    for (int j = 2; j < 4; ++j)
#pragma unroll
      for (int ks = 0; ks < 2; ++ks) b[j][ks] = rdB(pb, j, ks);
    if (!last) { stage(qb, Bg, 0, 64, t + 1); stage(qb, Bg, 128, 192, t + 1); }
    BAR();
    PHASE_MFMA(0, 1);
    if (!last) { VMCNT(4); } else { VMCNT(0); }   // R6,R7(t) done
    BAR();

    // ---------- phase 2: A(mh1) reads; MFMA quadrant (1,0)
#pragma unroll
    for (int i = 0; i < 4; ++i)
#pragma unroll
      for (int ks = 0; ks < 2; ++ks) a[i][ks] = rdA(pa, 4 + i, ks);
    if (!last) { stage(qb, Bg, 32, 96, t + 1); stage(qb, Bg, 160, 224, t + 1); }
    BAR();
    PHASE_MFMA(1, 0);
    BAR();                                         // no gate (P3 reads nothing)

    // ---------- phase 3: no reads; MFMA quadrant (1,1)
    if (!last) { stage(qa, Ag, 64, 96, t + 1); stage(qa, Ag, 192, 224, t + 1); }
    BAR();
    PHASE_MFMA(1, 1);
    if (!last) { VMCNT(4); }                       // R0-R3(t+1) done
    BAR();
  }

  // ---------- epilogue: bias + store (C/D layout: col=lane&15, row=(lane>>4)*4+reg)
  float bv[4];
#pragma unroll
  for (int nf = 0; nf < 4; ++nf) bv[nf] = bias[col0 + wc * 64 + nf * 16 + lr];
  const int orow = lk4 * 4;
#pragma unroll
  for (int mf = 0; mf < 8; ++mf) {
#pragma unroll
    for (int nf = 0; nf < 4; ++nf) {
      const int colg = col0 + wc * 64 + nf * 16 + lr;
#pragma unroll
      for (int r = 0; r < 4; ++r) {
        int rowg = row0 + wr * 128 + mf * 16 + orow + r;
        out[(size_t)rowg * N_DIM + colg] = acc[mf][nf][r] + bv[nf];
      }
    }
  }
#undef PHASE_MFMA
}

// ---------------- launch ----------------
extern "C" void kernel_launch(void* const* d_in, const int* in_sizes, int n_in,
                              void* d_out, int out_size, void* d_ws, size_t ws_size,
                              hipStream_t stream) {
  const float* input  = (const float*)d_in[0];
  const float* pweight = (const float*)d_in[1];
  const float* nweight = (const float*)d_in[2];
  const float* exps   = (const float*)d_in[3];
  const float* bexps  = (const float*)d_in[4];
  const float* maskw  = (const float*)d_in[5];
  const float* scale  = (const float*)d_in[6];
  const float* pbias  = (const float*)d_in[7];
  const float* nbias  = (const float*)d_in[8];
  const float* bscale = (const float*)d_in[9];
  float* out = (float*)d_out;

  unsigned short* Xb = (unsigned short*)d_ws;                                        // 64 MB
  unsigned short* Wb = (unsigned short*)((char*)d_ws + (size_t)M_DIM * K_DIM * 2);   // 8 MB
  float* bias = (float*)((char*)d_ws + (size_t)M_DIM * K_DIM * 2 + (size_t)N_DIM * K_DIM * 2);

  convert_x<<<(M_DIM * (size_t)K_DIM) / 8 / 256, 256, 0, stream>>>((const float4*)input, (uint4*)Xb);
  make_w<<<((size_t)N_DIM * K_DIM) / 256, 256, 0, stream>>>(
      (const float4*)pweight, (const float4*)nweight, exps, maskw, scale, Wb);
  make_bias<<<(N_DIM + 255) / 256, 256, 0, stream>>>(pbias, nbias, bexps, bscale, bias);

  dim3 grid((M_DIM / BM) * (N_DIM / BN));   // 64 * 8 = 512
  gemm_bias<<<grid, 512, 0, stream>>>(Xb, Wb, bias, out);
}

// Round 6
// 202.067 us; speedup vs baseline: 1.0640x; 1.0640x over previous
//
#include <hip/hip_runtime.h>
#include <hip/hip_bf16.h>
#include <stdint.h>

#define M_DIM 16384   // 8 * 2048
#define N_DIM 2048    // OUT_F
#define K_DIM 2048    // IN_F

typedef __attribute__((ext_vector_type(8))) __bf16 bf16x8;
typedef __attribute__((ext_vector_type(4))) float f32x4;

__device__ __forceinline__ unsigned short f2bf(float f) {
  unsigned int u = __builtin_bit_cast(unsigned int, f);
  u += 0x7FFFu + ((u >> 16) & 1u);   // round-to-nearest-even
  return (unsigned short)(u >> 16);
}

__device__ __forceinline__ float sigmoidf_(float x) {
  return 1.0f / (1.0f + __expf(-x));
}

// ---------------- kernel 1: X f32 -> bf16 ----------------
__global__ __launch_bounds__(256) void convert_x(const float4* __restrict__ x,
                                                 uint4* __restrict__ xb) {
  int idx = blockIdx.x * 256 + threadIdx.x;   // one uint4 (8 bf16) per thread
  float4 a = x[idx * 2];
  float4 b = x[idx * 2 + 1];
  uint4 r;
  r.x = (unsigned)f2bf(a.x) | ((unsigned)f2bf(a.y) << 16);
  r.y = (unsigned)f2bf(a.z) | ((unsigned)f2bf(a.w) << 16);
  r.z = (unsigned)f2bf(b.x) | ((unsigned)f2bf(b.y) << 16);
  r.w = (unsigned)f2bf(b.z) | ((unsigned)f2bf(b.w) << 16);
  xb[idx] = r;
}

// ---------------- kernel 2: weight materialization (producer-aligned) -------
// XCD x (blockIdx%8) materializes exactly B panel o in [x*256, x*256+256) --
// the panel GEMM-XCD x reads (B stays dirty-resident in its birth L2).
__global__ __launch_bounds__(256) void make_w(const float4* __restrict__ pw,
                                              const float4* __restrict__ nw,
                                              const float* __restrict__ exps,
                                              const float* __restrict__ maskw,
                                              const float* __restrict__ scale,
                                              unsigned short* __restrict__ wout) {
  const int beta = blockIdx.x;          // 16384 blocks
  const int xcd = beta & 7;
  const int j = beta >> 3;              // 0..2047
  const int o = xcd * 256 + (j >> 3);   // output row (B panel row)
  const int iblk = j & 7;               // 256-wide i chunk
  int idx = (o * 2048 + iblk * 256) + threadIdx.x;   // flat (o*K + i) in float4s
  float4 p = pw[idx];
  float4 n = nw[idx];
  float s = scale[0];
  float c0 = sigmoidf_(maskw[0]) * exps[0] * s;
  float c1 = sigmoidf_(maskw[1]) * exps[1] * s;
  float c2 = sigmoidf_(maskw[2]) * exps[2] * s;
  float c3 = sigmoidf_(maskw[3]) * exps[3] * s;
  float w = (sigmoidf_(p.x) - sigmoidf_(n.x)) * c0
          + (sigmoidf_(p.y) - sigmoidf_(n.y)) * c1
          + (sigmoidf_(p.z) - sigmoidf_(n.z)) * c2
          + (sigmoidf_(p.w) - sigmoidf_(n.w)) * c3;
  wout[idx] = f2bf(w);
}

// ---------------- kernel 3: bias ----------------
__global__ __launch_bounds__(256) void make_bias(const float* __restrict__ pb,
                                                 const float* __restrict__ nb,
                                                 const float* __restrict__ bexps,
                                                 const float* __restrict__ bscale,
                                                 float* __restrict__ bias) {
  int o = blockIdx.x * 256 + threadIdx.x;
  if (o < N_DIM) {
    float x = 0.f;
#pragma unroll
    for (int n = 0; n < 4; ++n) x += (pb[o * 4 + n] - nb[o * 4 + n]) * bexps[n];
    float xc = fminf(fmaxf(x, -1.f), 1.f);
    float mag = rintf(fabsf(xc) * 15.f) * (1.f / 15.f);
    float sgn = (xc > 0.f) ? 1.f : ((xc < 0.f) ? -1.f : 0.f);
    bias[o] = mag * sgn * bscale[0];
  }
}

// ---------------- kernel 4: 256x256 GEMM, barrier-halved 8-phase ------------
// R5 post-mortem: MfmaUtil pinned at 37-39% across 4 schedule variants; at
// 2 waves/SIMD (acc=128 AGPR, 1 block/CU -- register-file-forced) the
// mid-phase barrier locksteps both waves at the read/MFMA boundary, fully
// serializing the LDS pipe against the matrix pipe. The mid-barrier is
// semantically unneeded: every stage targets a region last ds_read >=4
// barriers earlier (WAR safe), gate-collectivity only needs gate-before-
// END-barrier (kept), and read->MFMA deps are register-tracked.
// Phase = {ds_reads; 2x stage; MFMA; [vmcnt gate]; s_barrier}  -- 4 bar/tile.
//
// Rounds (one gload_lds/thread, 64 rows): R0:A{0-63} R1:A{128-191}
// R2:B{0-31,64-95} R3:B{128-159,192-223} R4:B{32-63,96-127}
// R5:B{160-191,224-255} R6:A{64-127} R7:A{192-255}
// Staging: P0(t)->R0R1(t+1)  P1->R2R3  P2->R4R5  P3->R6R7  (into buf q).
// Reads:   P0(t): R0-R3(t)   P1: R4R5(t)  P2: R6R7(t)  P3: none.
// Gates (per-wave vmcnt, before end-barrier => collective after barrier):
//   end-P0 VMCNT(4) retires R4R5(t); end-P1 VMCNT(4) retires R6R7(t);
//   end-P2 none; end-P3 VMCNT(4) retires R0-R3(t+1). 3-phase slack each.

#define BM 256
#define BN 256
#define BK 64
#define NT (K_DIM / BK)   // 32

__device__ __forceinline__ void gload16(const void* g, void* l) {
  __builtin_amdgcn_global_load_lds(
      (const __attribute__((address_space(1))) unsigned int*)g,
      (__attribute__((address_space(3))) unsigned int*)l, 16, 0, 0);
}

#define VMCNT(n) asm volatile("s_waitcnt vmcnt(" #n ")" ::: "memory")
#define BAR() __builtin_amdgcn_s_barrier()

__global__ __launch_bounds__(512, 2) void gemm_bias(const unsigned short* __restrict__ X,
                                                    const unsigned short* __restrict__ W,
                                                    const float* __restrict__ bias,
                                                    float* __restrict__ out) {
  __shared__ unsigned short sA[2][BM * BK];   // 64 KiB
  __shared__ unsigned short sB[2][BN * BK];   // 64 KiB

  const int tid = threadIdx.x;
  // Locality swizzle (R5, kept): one bn-column per XCD; B panel L2-private.
  const int bn = (int)blockIdx.x & 7;    // == XCD (dispatch round-robin)
  const int bm = (int)blockIdx.x >> 3;   // 0..63
  const int row0 = bm * BM, col0 = bn * BN;

  const int w = tid >> 6, l = tid & 63;
  const int wr = w >> 2;        // 0..1  (M wave group)
  const int wc = w & 3;         // 0..3  (N wave group)
  const int lr = l & 15;
  const int lk4 = l >> 4;       // 0..3
  const int l7 = l & 7;

  const unsigned short* Ag = X + (size_t)row0 * K_DIM;
  const unsigned short* Bg = W + (size_t)col0 * K_DIM;

  // staging geometry: thread t -> row rb+((t>>3)&31); global col16 pre-swizzled
  const int srl = (tid >> 3) & 31;
  const int sc16 = (tid & 7) ^ ((tid >> 3) & 7);      // inverse-swizzled source
  const int shi = tid >> 8;                           // wave-uniform chunk select
  const int slin = ((tid >> 3) & 24) * 64 + (tid & 63) * 8;  // linear LDS dest

  auto stage = [&](unsigned short* lbase, const unsigned short* gbase,
                   int rb0, int rb1, int tk) {
    int rb = shi ? rb1 : rb0;
    int trow = rb + srl;
    gload16(gbase + (size_t)trow * K_DIM + tk * BK + sc16 * 8,
            lbase + rb * 64 + slin);
  };

  auto rdA = [&](const unsigned short* base, int mf, int ks) -> bf16x8 {
    int trow = wr * 128 + mf * 16 + lr;
    int c16l = (ks * 4 + lk4) ^ l7;
    return *(const bf16x8*)&base[trow * 64 + c16l * 8];
  };
  auto rdB = [&](const unsigned short* base, int nf, int ks) -> bf16x8 {
    int trow = wc * 64 + nf * 16 + lr;
    int c16l = (ks * 4 + lk4) ^ l7;
    return *(const bf16x8*)&base[trow * 64 + c16l * 8];
  };

  f32x4 acc[8][4] = {};
  bf16x8 a[4][2], b[4][2];

#define PHASE_MFMA(mh, nh)                                                    \
  __builtin_amdgcn_s_setprio(1);                                              \
  _Pragma("unroll") for (int i = 0; i < 4; ++i)                               \
  _Pragma("unroll") for (int j = 0; j < 2; ++j)                               \
  _Pragma("unroll") for (int ks = 0; ks < 2; ++ks)                            \
      acc[(mh) * 4 + i][(nh) * 2 + j] = __builtin_amdgcn_mfma_f32_16x16x32_bf16( \
          a[i][ks], b[(nh) * 2 + j][ks], acc[(mh) * 4 + i][(nh) * 2 + j], 0, 0, 0); \
  __builtin_amdgcn_s_setprio(0);

  // ---- prologue: stage tile 0 (rounds R0..R7, program order = round order)
  {
    unsigned short* qa = sA[0];
    unsigned short* qb = sB[0];
    stage(qa, Ag, 0, 32, 0);    // R0
    stage(qa, Ag, 128, 160, 0); // R1
    stage(qb, Bg, 0, 64, 0);    // R2
    stage(qb, Bg, 128, 192, 0); // R3
    stage(qb, Bg, 32, 96, 0);   // R4
    stage(qb, Bg, 160, 224, 0); // R5
    stage(qa, Ag, 64, 96, 0);   // R6
    stage(qa, Ag, 192, 224, 0); // R7
  }
  VMCNT(4);   // R0-R3(0) complete; R4-R7(0) in flight
  BAR();

  for (int t = 0; t < NT; ++t) {
    const int p = t & 1, q = p ^ 1;
    const bool last = (t == NT - 1);
    const unsigned short* pa = sA[p];
    const unsigned short* pb = sB[p];
    unsigned short* qa = sA[q];
    unsigned short* qb = sB[q];

    // ---- P0: reads A(mh0)+B(nf0,1) of t; stage R0R1(t+1); MFMA (0,0)
#pragma unroll
    for (int i = 0; i < 4; ++i)
#pragma unroll
      for (int ks = 0; ks < 2; ++ks) a[i][ks] = rdA(pa, i, ks);
#pragma unroll
    for (int j = 0; j < 2; ++j)
#pragma unroll
      for (int ks = 0; ks < 2; ++ks) b[j][ks] = rdB(pb, j, ks);
    if (!last) { stage(qa, Ag, 0, 32, t + 1); stage(qa, Ag, 128, 160, t + 1); }
    PHASE_MFMA(0, 0);
    if (!last) { VMCNT(4); } else { VMCNT(2); }   // R4,R5(t) done
    BAR();

    // ---- P1: reads B(nf2,3) of t; stage R2R3(t+1); MFMA (0,1)
#pragma unroll
    for (int j = 2; j < 4; ++j)
#pragma unroll
      for (int ks = 0; ks < 2; ++ks) b[j][ks] = rdB(pb, j, ks);
    if (!last) { stage(qb, Bg, 0, 64, t + 1); stage(qb, Bg, 128, 192, t + 1); }
    PHASE_MFMA(0, 1);
    if (!last) { VMCNT(4); } else { VMCNT(0); }   // R6,R7(t) done
    BAR();

    // ---- P2: reads A(mh1) of t; stage R4R5(t+1); MFMA (1,0)
#pragma unroll
    for (int i = 0; i < 4; ++i)
#pragma unroll
      for (int ks = 0; ks < 2; ++ks) a[i][ks] = rdA(pa, 4 + i, ks);
    if (!last) { stage(qb, Bg, 32, 96, t + 1); stage(qb, Bg, 160, 224, t + 1); }
    PHASE_MFMA(1, 0);
    BAR();                                         // no gate (P3 reads nothing)

    // ---- P3: no reads; stage R6R7(t+1); MFMA (1,1)
    if (!last) { stage(qa, Ag, 64, 96, t + 1); stage(qa, Ag, 192, 224, t + 1); }
    PHASE_MFMA(1, 1);
    if (!last) { VMCNT(4); }                       // R0-R3(t+1) done
    BAR();
  }

  // ---- epilogue: bias + store (C/D layout: col=lane&15, row=(lane>>4)*4+reg)
  float bv[4];
#pragma unroll
  for (int nf = 0; nf < 4; ++nf) bv[nf] = bias[col0 + wc * 64 + nf * 16 + lr];
  const int orow = lk4 * 4;
#pragma unroll
  for (int mf = 0; mf < 8; ++mf) {
#pragma unroll
    for (int nf = 0; nf < 4; ++nf) {
      const int colg = col0 + wc * 64 + nf * 16 + lr;
#pragma unroll
      for (int r = 0; r < 4; ++r) {
        int rowg = row0 + wr * 128 + mf * 16 + orow + r;
        out[(size_t)rowg * N_DIM + colg] = acc[mf][nf][r] + bv[nf];
      }
    }
  }
#undef PHASE_MFMA
}

// ---------------- launch ----------------
extern "C" void kernel_launch(void* const* d_in, const int* in_sizes, int n_in,
                              void* d_out, int out_size, void* d_ws, size_t ws_size,
                              hipStream_t stream) {
  const float* input  = (const float*)d_in[0];
  const float* pweight = (const float*)d_in[1];
  const float* nweight = (const float*)d_in[2];
  const float* exps   = (const float*)d_in[3];
  const float* bexps  = (const float*)d_in[4];
  const float* maskw  = (const float*)d_in[5];
  const float* scale  = (const float*)d_in[6];
  const float* pbias  = (const float*)d_in[7];
  const float* nbias  = (const float*)d_in[8];
  const float* bscale = (const float*)d_in[9];
  float* out = (float*)d_out;

  unsigned short* Xb = (unsigned short*)d_ws;                                        // 64 MB
  unsigned short* Wb = (unsigned short*)((char*)d_ws + (size_t)M_DIM * K_DIM * 2);   // 8 MB
  float* bias = (float*)((char*)d_ws + (size_t)M_DIM * K_DIM * 2 + (size_t)N_DIM * K_DIM * 2);

  convert_x<<<(M_DIM * (size_t)K_DIM) / 8 / 256, 256, 0, stream>>>((const float4*)input, (uint4*)Xb);
  make_w<<<((size_t)N_DIM * K_DIM) / 256, 256, 0, stream>>>(
      (const float4*)pweight, (const float4*)nweight, exps, maskw, scale, Wb);
  make_bias<<<(N_DIM + 255) / 256, 256, 0, stream>>>(pbias, nbias, bexps, bscale, bias);

  dim3 grid((M_DIM / BM) * (N_DIM / BN));   // 64 * 8 = 512
  gemm_bias<<<grid, 512, 0, stream>>>(Xb, Wb, bias, out);
}